// Round 1
// baseline (637.541 us; speedup 1.0000x reference)
//
#include <hip/hip_runtime.h>
#include <cstddef>

// Problem constants (B,T,D fixed by the reference).
#define B_ 8
#define T_ 4096
#define D_ 1024
#define M_ (B_*T_)        // 32768 rows
#define K_ 1024           // reduction dim
#define NC 32             // scan chunks per sequence
#define CL (T_/NC)        // 128 steps per chunk

// GEMM tile config
#define BM 128
#define BN 128
#define BK 32
#define LDA 40            // padded LDS row stride (shorts) -> 80B, 16B-aligned, conflict-light

typedef __bf16 bf16x4 __attribute__((ext_vector_type(4)));
typedef __bf16 bf16x8 __attribute__((ext_vector_type(8)));
typedef float  f32x4  __attribute__((ext_vector_type(4)));

// ---------------------------------------------------------------------------
// K1: fused dual-GEMM + gate epilogue.
// Computes zr = x @ Wa^T + ba, zi = x @ Wx^T + bx for a 128x128 (M x N) tile,
// then per element: r=sig(zr), i=sig(zi), e=8*r*log2(sig(lambda)),
// a=2^e, gate=sqrt(max(1-a^2,1e-6)), gx=gate*i*x.
// Writes e (bf16) to ws and gx (fp32) to d_out.
// ---------------------------------------------------------------------------
__global__ __launch_bounds__(256) void rg_gemm_gate(
    const float* __restrict__ X, const float* __restrict__ Wa,
    const float* __restrict__ Wx, const float* __restrict__ Ba,
    const float* __restrict__ Bx, const float* __restrict__ LL,
    __bf16* __restrict__ EB, float* __restrict__ GX)
{
    __shared__ __bf16 Al[BM * LDA];
    __shared__ __bf16 Br[BN * LDA];
    __shared__ __bf16 Bi[BN * LDA];

    const int tid  = threadIdx.x;
    const int lane = tid & 63;
    const int w    = tid >> 6;
    const int wr   = (w >> 1) * 64;   // wave row offset in tile
    const int wc   = (w & 1) * 64;    // wave col offset in tile
    const int bid  = blockIdx.x;
    const int n0   = (bid & 7) * BN;  // 1024/128 = 8 n-tiles
    const int m0   = (bid >> 3) * BM;

    f32x4 accr[4][4] = {};
    f32x4 acci[4][4] = {};

    const int lrow = lane & 15;
    const int lko  = (lane >> 4) << 3;   // k offset of this lane's 8-elem fragment

    for (int k0 = 0; k0 < K_; k0 += BK) {
        // ---- stage A (x), B_r (Wa), B_i (Wx): fp32 -> bf16 into LDS ----
        #pragma unroll
        for (int i = 0; i < 4; ++i) {
            const int fid = tid + i * 256;
            const int r   = fid >> 3;
            const int c4  = (fid & 7) << 2;
            float4 v = *reinterpret_cast<const float4*>(X + (size_t)(m0 + r) * K_ + k0 + c4);
            bf16x4 s;
            s[0] = (__bf16)v.x; s[1] = (__bf16)v.y; s[2] = (__bf16)v.z; s[3] = (__bf16)v.w;
            *reinterpret_cast<bf16x4*>(&Al[r * LDA + c4]) = s;
        }
        #pragma unroll
        for (int i = 0; i < 4; ++i) {
            const int fid = tid + i * 256;
            const int r   = fid >> 3;
            const int c4  = (fid & 7) << 2;
            float4 v = *reinterpret_cast<const float4*>(Wa + (size_t)(n0 + r) * K_ + k0 + c4);
            bf16x4 s;
            s[0] = (__bf16)v.x; s[1] = (__bf16)v.y; s[2] = (__bf16)v.z; s[3] = (__bf16)v.w;
            *reinterpret_cast<bf16x4*>(&Br[r * LDA + c4]) = s;
        }
        #pragma unroll
        for (int i = 0; i < 4; ++i) {
            const int fid = tid + i * 256;
            const int r   = fid >> 3;
            const int c4  = (fid & 7) << 2;
            float4 v = *reinterpret_cast<const float4*>(Wx + (size_t)(n0 + r) * K_ + k0 + c4);
            bf16x4 s;
            s[0] = (__bf16)v.x; s[1] = (__bf16)v.y; s[2] = (__bf16)v.z; s[3] = (__bf16)v.w;
            *reinterpret_cast<bf16x4*>(&Bi[r * LDA + c4]) = s;
        }
        __syncthreads();

        // ---- fragments + MFMA ----
        bf16x8 af[4], brf[4], bif[4];
        #pragma unroll
        for (int mi = 0; mi < 4; ++mi)
            af[mi] = *reinterpret_cast<const bf16x8*>(&Al[(wr + mi * 16 + lrow) * LDA + lko]);
        #pragma unroll
        for (int ni = 0; ni < 4; ++ni) {
            brf[ni] = *reinterpret_cast<const bf16x8*>(&Br[(wc + ni * 16 + lrow) * LDA + lko]);
            bif[ni] = *reinterpret_cast<const bf16x8*>(&Bi[(wc + ni * 16 + lrow) * LDA + lko]);
        }
        #pragma unroll
        for (int mi = 0; mi < 4; ++mi) {
            #pragma unroll
            for (int ni = 0; ni < 4; ++ni) {
                accr[mi][ni] = __builtin_amdgcn_mfma_f32_16x16x32_bf16(af[mi], brf[ni], accr[mi][ni], 0, 0, 0);
                acci[mi][ni] = __builtin_amdgcn_mfma_f32_16x16x32_bf16(af[mi], bif[ni], acci[mi][ni], 0, 0, 0);
            }
        }
        __syncthreads();
    }

    // ---- epilogue: C/D layout col = lane&15, row = (lane>>4)*4 + j ----
    const int rbase = m0 + wr + ((lane >> 4) << 2);
    const int cbase = n0 + wc + lrow;
    #pragma unroll
    for (int ni = 0; ni < 4; ++ni) {
        const int col = cbase + ni * 16;
        const float lam = LL[col];
        const float l2s = -log2f(1.0f + __expf(-lam));  // log2(sigmoid(lambda))
        const float bav = Ba[col];
        const float bxv = Bx[col];
        #pragma unroll
        for (int mi = 0; mi < 4; ++mi) {
            #pragma unroll
            for (int j = 0; j < 4; ++j) {
                const int row = rbase + mi * 16 + j;
                const float zr = accr[mi][ni][j] + bav;
                const float zi = acci[mi][ni][j] + bxv;
                const float rv = 1.0f / (1.0f + __expf(-zr));
                const float iv = 1.0f / (1.0f + __expf(-zi));
                const float ee = 8.0f * rv * l2s;       // log2(a)
                const float a  = exp2f(ee);
                const float gate = sqrtf(fmaxf((1.0f - a) * (1.0f + a), 1e-6f));
                const size_t idx = (size_t)row * D_ + col;
                EB[idx] = (__bf16)ee;
                GX[idx] = gate * iv * X[idx];
            }
        }
    }
}

// ---------------------------------------------------------------------------
// K2: per-chunk summaries. For chunk c of sequence (b, d):
//   P = 2^(sum e_t)  (product of a over the chunk)
//   hend = local scan of (a, gx) starting from h=0
// ---------------------------------------------------------------------------
__global__ __launch_bounds__(256) void rg_scan_chunks(
    const __bf16* __restrict__ EB, const float* __restrict__ GX,
    float* __restrict__ P, float* __restrict__ HE)
{
    const int g = blockIdx.x * 256 + threadIdx.x;   // < B*NC*D = 262144
    const int d = g & (D_ - 1);
    const int c = (g >> 10) & (NC - 1);
    const int b = g >> 15;
    const size_t base = ((size_t)(b * T_ + c * CL)) * D_ + d;

    float h = 0.0f;
    float se = 0.0f;
    #pragma unroll 4
    for (int t = 0; t < CL; ++t) {
        const float e  = (float)EB[base + (size_t)t * D_];
        const float gx = GX[base + (size_t)t * D_];
        h = fmaf(exp2f(e), h, gx);
        se += e;
    }
    const int sidx = (b * NC + c) * D_ + d;
    P[sidx]  = exp2f(se);
    HE[sidx] = h;
}

// ---------------------------------------------------------------------------
// K3: sequential combine over NC chunks per (b,d). Seeds with h0.
// Writes carry-in per chunk and the final hidden state to d_out tail.
// ---------------------------------------------------------------------------
__global__ __launch_bounds__(256) void rg_combine(
    const float* __restrict__ P, const float* __restrict__ HE,
    const float* __restrict__ H0, float* __restrict__ CI,
    float* __restrict__ HF)
{
    const int g = blockIdx.x * 256 + threadIdx.x;   // < B*D = 8192
    const int d = g & (D_ - 1);
    const int b = g >> 10;
    float carry = H0[g];
    #pragma unroll
    for (int c = 0; c < NC; ++c) {
        const int sidx = (b * NC + c) * D_ + d;
        CI[sidx] = carry;
        carry = fmaf(P[sidx], carry, HE[sidx]);
    }
    HF[g] = carry;
}

// ---------------------------------------------------------------------------
// K4: final intra-chunk scan with correct carry; reads gx from d_out and
// overwrites it in place with h_t.
// ---------------------------------------------------------------------------
__global__ __launch_bounds__(256) void rg_scan_final(
    const __bf16* __restrict__ EB, const float* __restrict__ CI,
    float* __restrict__ OUT)
{
    const int g = blockIdx.x * 256 + threadIdx.x;   // < B*NC*D
    const int d = g & (D_ - 1);
    const int c = (g >> 10) & (NC - 1);
    const int b = g >> 15;
    const size_t base = ((size_t)(b * T_ + c * CL)) * D_ + d;

    float h = CI[(b * NC + c) * D_ + d];
    #pragma unroll 4
    for (int t = 0; t < CL; ++t) {
        const size_t idx = base + (size_t)t * D_;
        const float e  = (float)EB[idx];
        const float gx = OUT[idx];
        h = fmaf(exp2f(e), h, gx);
        OUT[idx] = h;
    }
}

// ---------------------------------------------------------------------------
extern "C" void kernel_launch(void* const* d_in, const int* in_sizes, int n_in,
                              void* d_out, int out_size, void* d_ws, size_t ws_size,
                              hipStream_t stream)
{
    const float* X  = (const float*)d_in[0];
    const float* H0 = (const float*)d_in[1];
    const float* Wa = (const float*)d_in[2];
    const float* Ba = (const float*)d_in[3];
    const float* Wx = (const float*)d_in[4];
    const float* Bx = (const float*)d_in[5];
    const float* LL = (const float*)d_in[6];
    float* OUT = (float*)d_out;

    // ws layout: e (bf16, 64MB) | P | HE | CI  (floats, 1MB each)
    char* ws = (char*)d_ws;
    __bf16* EB = (__bf16*)ws;
    float* P  = (float*)(ws + (size_t)M_ * D_ * 2);
    float* HE = P  + (size_t)B_ * NC * D_;
    float* CI = HE + (size_t)B_ * NC * D_;

    float* HFINAL = OUT + (size_t)M_ * D_;   // h_final after outputs

    rg_gemm_gate<<<dim3((M_ / BM) * (D_ / BN)), dim3(256), 0, stream>>>(
        X, Wa, Wx, Ba, Bx, LL, EB, OUT);
    rg_scan_chunks<<<dim3(B_ * NC * D_ / 256), dim3(256), 0, stream>>>(EB, OUT, P, HE);
    rg_combine<<<dim3(B_ * D_ / 256), dim3(256), 0, stream>>>(P, HE, H0, CI, HFINAL);
    rg_scan_final<<<dim3(B_ * NC * D_ / 256), dim3(256), 0, stream>>>(EB, CI, OUT);
}

// Round 2
// 452.676 us; speedup vs baseline: 1.4084x; 1.4084x over previous
//
#include <hip/hip_runtime.h>
#include <cstddef>
#include <cstdint>

// Problem constants (B,T,D fixed by the reference).
#define B_ 8
#define T_ 4096
#define D_ 1024
#define M_ (B_*T_)        // 32768 rows
#define K_ 1024
#define NC 32             // scan chunks per sequence
#define CL (T_/NC)        // 128 steps per chunk

// GEMM tile config
#define BM 128
#define BN 128
#define BK 64
#define LDAP 72           // padded A stride (shorts) for the fallback path

typedef __bf16 bf16x8 __attribute__((ext_vector_type(8)));
typedef float  f32x4  __attribute__((ext_vector_type(4)));

__device__ __forceinline__ void gload_lds16(const __bf16* g, __bf16* l) {
    __builtin_amdgcn_global_load_lds(
        (const __attribute__((address_space(1))) void*)g,
        (__attribute__((address_space(3))) void*)l, 16, 0, 0);
}

// ---------------------------------------------------------------------------
// cvt_swz: fp32 [rows][1024] -> bf16, reorganized into 16 k-chunks of 64 cols,
// each row 128B, XOR-swizzled within the row: byte ^= (row&7)<<4.
// This is the *inverse-swizzled source* so that linear global_load_lds staging
// lands the swizzle in LDS, and ds_read applies the same XOR (G21).
// ---------------------------------------------------------------------------
__global__ __launch_bounds__(256) void cvt_swz(const float* __restrict__ src,
                                               __bf16* __restrict__ dst, int rows)
{
    const int g  = blockIdx.x * 256 + threadIdx.x;   // rows*128 threads
    const int r  = g >> 7;
    const int k0 = (g & 127) << 3;                   // 8 elems per thread
    const int kc = k0 >> 6;
    const int jj = k0 & 63;
    const float4 v0 = *reinterpret_cast<const float4*>(src + (size_t)r * 1024 + k0);
    const float4 v1 = *reinterpret_cast<const float4*>(src + (size_t)r * 1024 + k0 + 4);
    bf16x8 s;
    s[0]=(__bf16)v0.x; s[1]=(__bf16)v0.y; s[2]=(__bf16)v0.z; s[3]=(__bf16)v0.w;
    s[4]=(__bf16)v1.x; s[5]=(__bf16)v1.y; s[6]=(__bf16)v1.z; s[7]=(__bf16)v1.w;
    const uint32_t inrow = (uint32_t)(r * 128 + (jj << 1)) ^ (uint32_t)((r & 7) << 4);
    const size_t byteoff = (size_t)kc * ((size_t)rows * 128) + inrow;
    *reinterpret_cast<bf16x8*>(reinterpret_cast<char*>(dst) + byteoff) = s;
}

// ---------------------------------------------------------------------------
// K1: fused dual-GEMM + gate epilogue.  zr = x@Wa^T + ba, zi = x@Wx^T + bx,
// r=sig(zr), i=sig(zi), e=8*r*log2(sig(lambda)), a=2^e,
// gate=sqrt(max(1-a^2,1e-6)), gx=gate*i*x.  e (bf16)->ws, gx (fp32)->d_out.
// XPRE: A staged via global_load_lds from pre-swizzled bf16 X.
// !XPRE: A reg-staged from fp32 X (cvt in-loop), padded LDS stride.
// ---------------------------------------------------------------------------
template<bool XPRE>
__global__ __launch_bounds__(256, 2) void rg_gemm_gate(
    const float* __restrict__ Xf, const __bf16* __restrict__ Xsw,
    const __bf16* __restrict__ Wasw, const __bf16* __restrict__ Wxsw,
    const float* __restrict__ Ba, const float* __restrict__ Bx,
    const float* __restrict__ LL,
    __bf16* __restrict__ EB, float* __restrict__ GX)
{
    constexpr int ASTR = XPRE ? 64 : LDAP;
    __shared__ __bf16 Al[BM * ASTR];
    __shared__ __bf16 Br[BN * 64];
    __shared__ __bf16 Bi[BN * 64];

    const int tid  = threadIdx.x;
    const int lane = tid & 63;
    const int w    = tid >> 6;
    const int wr   = (w >> 1) * 64;
    const int wc   = (w & 1) * 64;

    // XCD-aware swizzle: nwg=2048 (divisible by 8); n-tile fastest within XCD
    // so the 8 blocks sharing an A-panel are L2-local.
    const int bid  = blockIdx.x;
    const int wgid = (bid & 7) * 256 + (bid >> 3);
    const int n0   = (wgid & 7) << 7;
    const int m0   = (wgid >> 3) << 7;

    const int lrow = lane & 15;
    const int lko  = (lane >> 4) << 3;

    f32x4 accr[4][4] = {};
    f32x4 acci[4][4] = {};

    for (int kc = 0; kc < 16; ++kc) {
        __syncthreads();   // previous compute done before LDS overwrite
        // ---- stage Br, Bi: linear gl_lds from pre-swizzled weights ----
        {
            const size_t cb = (size_t)kc * (1024 * 64) + (size_t)n0 * 64;
            #pragma unroll
            for (int c = 0; c < 4; ++c) {
                const int off = (w * 4 + c) * 512;      // shorts; 1KB per call
                gload_lds16(Wasw + cb + off + lane * 8, &Br[off]);
                gload_lds16(Wxsw + cb + off + lane * 8, &Bi[off]);
            }
        }
        // ---- stage A ----
        if (XPRE) {
            const size_t cb = (size_t)kc * ((size_t)M_ * 64) + (size_t)m0 * 64;
            #pragma unroll
            for (int c = 0; c < 4; ++c) {
                const int off = (w * 4 + c) * 512;
                gload_lds16(Xsw + cb + off + lane * 8, &Al[off]);
            }
        } else {
            const int row = tid >> 1;
            const int c0  = (tid & 1) * 32;
            const float* xr = Xf + (size_t)(m0 + row) * K_ + kc * 64 + c0;
            #pragma unroll
            for (int gq = 0; gq < 4; ++gq) {
                const float4 v0 = *reinterpret_cast<const float4*>(xr + gq * 8);
                const float4 v1 = *reinterpret_cast<const float4*>(xr + gq * 8 + 4);
                bf16x8 s;
                s[0]=(__bf16)v0.x; s[1]=(__bf16)v0.y; s[2]=(__bf16)v0.z; s[3]=(__bf16)v0.w;
                s[4]=(__bf16)v1.x; s[5]=(__bf16)v1.y; s[6]=(__bf16)v1.z; s[7]=(__bf16)v1.w;
                *reinterpret_cast<bf16x8*>(&Al[row * LDAP + c0 + gq * 8]) = s;
            }
        }
        __syncthreads();

        // ---- compute: 2 k-subtiles x 16 (m,n) x 2 gemms = 64 MFMA ----
        #pragma unroll
        for (int ksub = 0; ksub < 2; ++ksub) {
            bf16x8 af[4], brf[4], bif[4];
            #pragma unroll
            for (int mi = 0; mi < 4; ++mi) {
                const int ra = wr + mi * 16 + lrow;
                if (XPRE) {
                    const uint32_t bo = (uint32_t)(ra * 128 + ksub * 64 + (lko << 1))
                                      ^ (uint32_t)((ra & 7) << 4);
                    af[mi] = *reinterpret_cast<const bf16x8*>(
                        reinterpret_cast<const char*>(Al) + bo);
                } else {
                    af[mi] = *reinterpret_cast<const bf16x8*>(
                        &Al[ra * LDAP + ksub * 32 + lko]);
                }
            }
            #pragma unroll
            for (int ni = 0; ni < 4; ++ni) {
                const int rb = wc + ni * 16 + lrow;
                const uint32_t bo = (uint32_t)(rb * 128 + ksub * 64 + (lko << 1))
                                  ^ (uint32_t)((rb & 7) << 4);
                brf[ni] = *reinterpret_cast<const bf16x8*>(
                    reinterpret_cast<const char*>(Br) + bo);
                bif[ni] = *reinterpret_cast<const bf16x8*>(
                    reinterpret_cast<const char*>(Bi) + bo);
            }
            #pragma unroll
            for (int mi = 0; mi < 4; ++mi) {
                #pragma unroll
                for (int ni = 0; ni < 4; ++ni) {
                    accr[mi][ni] = __builtin_amdgcn_mfma_f32_16x16x32_bf16(
                        af[mi], brf[ni], accr[mi][ni], 0, 0, 0);
                    acci[mi][ni] = __builtin_amdgcn_mfma_f32_16x16x32_bf16(
                        af[mi], bif[ni], acci[mi][ni], 0, 0, 0);
                }
            }
        }
    }

    // ---- epilogue: C/D layout col = lane&15, row = (lane>>4)*4 + j ----
    const int rbase = m0 + wr + ((lane >> 4) << 2);
    const int cbase = n0 + wc + lrow;
    #pragma unroll
    for (int ni = 0; ni < 4; ++ni) {
        const int col = cbase + ni * 16;
        const float lam = LL[col];
        const float l2s = -log2f(1.0f + __expf(-lam));  // log2(sigmoid(lambda))
        const float bav = Ba[col];
        const float bxv = Bx[col];
        #pragma unroll
        for (int mi = 0; mi < 4; ++mi) {
            #pragma unroll
            for (int j = 0; j < 4; ++j) {
                const int row = rbase + mi * 16 + j;
                const float zr = accr[mi][ni][j] + bav;
                const float zi = acci[mi][ni][j] + bxv;
                const float rv = 1.0f / (1.0f + __expf(-zr));
                const float iv = 1.0f / (1.0f + __expf(-zi));
                const float ee = 8.0f * rv * l2s;       // log2(a)
                const float a  = exp2f(ee);
                const float gate = sqrtf(fmaxf((1.0f - a) * (1.0f + a), 1e-6f));
                const size_t idx = (size_t)row * D_ + col;
                EB[idx] = (__bf16)ee;
                GX[idx] = gate * iv * Xf[idx];
            }
        }
    }
}

// ---------------------------------------------------------------------------
// K2: per-chunk summaries: P = prod a, hend = local scan from 0.
// ---------------------------------------------------------------------------
__global__ __launch_bounds__(256) void rg_scan_chunks(
    const __bf16* __restrict__ EB, const float* __restrict__ GX,
    float* __restrict__ P, float* __restrict__ HE)
{
    const int g = blockIdx.x * 256 + threadIdx.x;   // < B*NC*D = 262144
    const int d = g & (D_ - 1);
    const int c = (g >> 10) & (NC - 1);
    const int b = g >> 15;
    const size_t base = ((size_t)(b * T_ + c * CL)) * D_ + d;

    float h = 0.0f;
    float se = 0.0f;
    #pragma unroll 4
    for (int t = 0; t < CL; ++t) {
        const float e  = (float)EB[base + (size_t)t * D_];
        const float gx = GX[base + (size_t)t * D_];
        h = fmaf(exp2f(e), h, gx);
        se += e;
    }
    const int sidx = (b * NC + c) * D_ + d;
    P[sidx]  = exp2f(se);
    HE[sidx] = h;
}

// ---------------------------------------------------------------------------
// K3: sequential combine over NC chunks per (b,d); seeds with h0.
// ---------------------------------------------------------------------------
__global__ __launch_bounds__(256) void rg_combine(
    const float* __restrict__ P, const float* __restrict__ HE,
    const float* __restrict__ H0, float* __restrict__ CI,
    float* __restrict__ HF)
{
    const int g = blockIdx.x * 256 + threadIdx.x;   // < B*D = 8192
    const int d = g & (D_ - 1);
    const int b = g >> 10;
    float carry = H0[g];
    #pragma unroll
    for (int c = 0; c < NC; ++c) {
        const int sidx = (b * NC + c) * D_ + d;
        CI[sidx] = carry;
        carry = fmaf(P[sidx], carry, HE[sidx]);
    }
    HF[g] = carry;
}

// ---------------------------------------------------------------------------
// K4: final intra-chunk scan; reads gx from d_out, overwrites with h_t.
// ---------------------------------------------------------------------------
__global__ __launch_bounds__(256) void rg_scan_final(
    const __bf16* __restrict__ EB, const float* __restrict__ CI,
    float* __restrict__ OUT)
{
    const int g = blockIdx.x * 256 + threadIdx.x;   // < B*NC*D
    const int d = g & (D_ - 1);
    const int c = (g >> 10) & (NC - 1);
    const int b = g >> 15;
    const size_t base = ((size_t)(b * T_ + c * CL)) * D_ + d;

    float h = CI[(b * NC + c) * D_ + d];
    #pragma unroll 4
    for (int t = 0; t < CL; ++t) {
        const size_t idx = base + (size_t)t * D_;
        const float e  = (float)EB[idx];
        const float gx = OUT[idx];
        h = fmaf(exp2f(e), h, gx);
        OUT[idx] = h;
    }
}

// ---------------------------------------------------------------------------
extern "C" void kernel_launch(void* const* d_in, const int* in_sizes, int n_in,
                              void* d_out, int out_size, void* d_ws, size_t ws_size,
                              hipStream_t stream)
{
    const float* X  = (const float*)d_in[0];
    const float* H0 = (const float*)d_in[1];
    const float* Wa = (const float*)d_in[2];
    const float* Ba = (const float*)d_in[3];
    const float* Wx = (const float*)d_in[4];
    const float* Bx = (const float*)d_in[5];
    const float* LL = (const float*)d_in[6];
    float* OUT = (float*)d_out;

    // ws layout: EB (bf16, 64MB) | P | HE | CI (1MB each) | Wasw | Wxsw (2MB each)
    //            | Xsw (bf16, 64MB — only if ws_size permits)
    char* ws = (char*)d_ws;
    __bf16* EB = (__bf16*)ws;
    size_t off = (size_t)M_ * D_ * 2;
    float* P  = (float*)(ws + off); off += (size_t)B_ * NC * D_ * 4;
    float* HE = (float*)(ws + off); off += (size_t)B_ * NC * D_ * 4;
    float* CI = (float*)(ws + off); off += (size_t)B_ * NC * D_ * 4;
    __bf16* Wasw = (__bf16*)(ws + off); off += (size_t)K_ * D_ * 2;
    __bf16* Wxsw = (__bf16*)(ws + off); off += (size_t)K_ * D_ * 2;
    __bf16* Xsw  = (__bf16*)(ws + off);
    const size_t need_x = off + (size_t)M_ * K_ * 2;
    const bool xpre = (ws_size >= need_x);

    float* HFINAL = OUT + (size_t)M_ * D_;   // h_final after outputs

    // Weight conversion (always): 1024 rows each -> 512 blocks.
    cvt_swz<<<dim3(512), dim3(256), 0, stream>>>(Wa, Wasw, 1024);
    cvt_swz<<<dim3(512), dim3(256), 0, stream>>>(Wx, Wxsw, 1024);
    if (xpre) {
        cvt_swz<<<dim3(M_ / 2), dim3(256), 0, stream>>>(X, Xsw, M_);
        rg_gemm_gate<true><<<dim3((M_/BM) * (D_/BN)), dim3(256), 0, stream>>>(
            X, Xsw, Wasw, Wxsw, Ba, Bx, LL, EB, OUT);
    } else {
        rg_gemm_gate<false><<<dim3((M_/BM) * (D_/BN)), dim3(256), 0, stream>>>(
            X, Xsw, Wasw, Wxsw, Ba, Bx, LL, EB, OUT);
    }
    rg_scan_chunks<<<dim3(B_ * NC * D_ / 256), dim3(256), 0, stream>>>(EB, OUT, P, HE);
    rg_combine<<<dim3(B_ * D_ / 256), dim3(256), 0, stream>>>(P, HE, H0, CI, HFINAL);
    rg_scan_final<<<dim3(B_ * NC * D_ / 256), dim3(256), 0, stream>>>(EB, CI, OUT);
}

// Round 3
// 270.621 us; speedup vs baseline: 2.3558x; 1.6727x over previous
//
#include <hip/hip_runtime.h>
#include <cstddef>
#include <cstdint>

// Problem constants (B,T,D fixed by the reference).
#define B_ 8
#define T_ 4096
#define D_ 1024
#define M_ (B_*T_)        // 32768 rows
#define K_ 1024
#define NC 32             // scan chunks per sequence
#define CL 128            // steps per chunk

// GEMM tile config: 256x128 output tile, dual-B (r and i), BK=64, 8 waves.
#define BM 256
#define BN 128

typedef __bf16 bf16x8 __attribute__((ext_vector_type(8)));
typedef float  f32x4  __attribute__((ext_vector_type(4)));

__device__ __forceinline__ void gload_lds16(const __bf16* g, __bf16* l) {
    __builtin_amdgcn_global_load_lds(
        (const __attribute__((address_space(1))) void*)g,
        (__attribute__((address_space(3))) void*)l, 16, 0, 0);
}

__device__ __forceinline__ float bfbits2f(uint32_t hi16_as_low) {
    return __builtin_bit_cast(float, hi16_as_low);
}

// ---------------------------------------------------------------------------
// cvt_swz: fp32 [rows][1024] -> bf16, reorganized into 16 k-chunks of 64 cols,
// each row 128B, XOR-swizzled within the row: byte ^= (row&7)<<4.
// Inverse-swizzled source so linear global_load_lds lands the swizzle in LDS
// and ds_read applies the same XOR (G21). Zero bank conflicts verified (R2).
// ---------------------------------------------------------------------------
__global__ __launch_bounds__(256) void cvt_swz(const float* __restrict__ src,
                                               __bf16* __restrict__ dst, int rows)
{
    const int g  = blockIdx.x * 256 + threadIdx.x;   // rows*128 threads
    const int r  = g >> 7;
    const int k0 = (g & 127) << 3;                   // 8 elems per thread
    const int kc = k0 >> 6;
    const int jj = k0 & 63;
    const float4 v0 = *reinterpret_cast<const float4*>(src + (size_t)r * 1024 + k0);
    const float4 v1 = *reinterpret_cast<const float4*>(src + (size_t)r * 1024 + k0 + 4);
    bf16x8 s;
    s[0]=(__bf16)v0.x; s[1]=(__bf16)v0.y; s[2]=(__bf16)v0.z; s[3]=(__bf16)v0.w;
    s[4]=(__bf16)v1.x; s[5]=(__bf16)v1.y; s[6]=(__bf16)v1.z; s[7]=(__bf16)v1.w;
    const uint32_t inrow = (uint32_t)(r * 128 + (jj << 1)) ^ (uint32_t)((r & 7) << 4);
    const size_t byteoff = (size_t)kc * ((size_t)rows * 128) + inrow;
    *reinterpret_cast<bf16x8*>(reinterpret_cast<char*>(dst) + byteoff) = s;
}

// ---------------------------------------------------------------------------
// K1: fused dual-GEMM + slim gate epilogue, 2-phase counted-vmcnt pipeline.
// zr = x@Wa^T + ba, zi = x@Wx^T + bx; r=sig(zr), i=sig(zi);
// e = 8*r*log2(sig(lambda)); stores packed dword {lo: bf16(e), hi: bf16(i*x)}.
// a/gate/gx reconstruction is deferred to the scan kernels.
// ---------------------------------------------------------------------------
__global__ __launch_bounds__(512, 1) void rg_gemm_gate(
    const __bf16* __restrict__ Xsw, const __bf16* __restrict__ Wasw,
    const __bf16* __restrict__ Wxsw, const float* __restrict__ Ba,
    const float* __restrict__ Bx, const float* __restrict__ LL,
    uint32_t* __restrict__ EIX)
{
    __shared__ __bf16 Al [2][BM * 64];   // 64 KiB
    __shared__ __bf16 Brs[2][BN * 64];   // 32 KiB
    __shared__ __bf16 Bis[2][BN * 64];   // 32 KiB

    const int tid  = threadIdx.x;
    const int lane = tid & 63;
    const int w    = tid >> 6;           // 8 waves: 4M x 2N
    const int wr   = (w >> 1) * 64;
    const int wc   = (w & 1) * 64;

    // XCD swizzle (1024 blocks, %8==0): n-tile fastest within each XCD.
    const int bid  = blockIdx.x;
    const int wgid = (bid & 7) * 128 + (bid >> 3);
    const int n0   = (wgid & 7) << 7;    // 8 n-tiles
    const int m0   = (wgid >> 3) << 8;   // 128 m-tiles

    const int lrow = lane & 15;
    const int lkb  = (lane >> 4) << 4;   // byte offset of k-fragment in row

    f32x4 accr[4][4] = {};
    f32x4 acci[4][4] = {};

    // Per-wave stage = 8 global_load_lds (A:4, Br:2, Bi:2), 1 KiB each.
    auto STAGE = [&](int buf, int kc) {
        const size_t cbA = (size_t)kc * ((size_t)M_ * 64) + (size_t)m0 * 64;
        const size_t cbB = (size_t)kc * (1024 * 64) + (size_t)n0 * 64;
        #pragma unroll
        for (int c = 0; c < 4; ++c) {
            const int j = (c * 8 + w) * 512;
            gload_lds16(Xsw + cbA + j + lane * 8, &Al[buf][j]);
        }
        #pragma unroll
        for (int c = 0; c < 2; ++c) {
            const int j = (c * 8 + w) * 512;
            gload_lds16(Wasw + cbB + j + lane * 8, &Brs[buf][j]);
            gload_lds16(Wxsw + cbB + j + lane * 8, &Bis[buf][j]);
        }
    };

    STAGE(0, 0);
    for (int kc = 0; kc < 16; ++kc) {
        const int cur = kc & 1;
        if (kc < 15) {
            STAGE(cur ^ 1, kc + 1);
            asm volatile("s_waitcnt vmcnt(8)" ::: "memory");  // buf[cur] landed; next 8 in flight
        } else {
            asm volatile("s_waitcnt vmcnt(0)" ::: "memory");
        }
        __builtin_amdgcn_s_barrier();

        const char* Ab = reinterpret_cast<const char*>(Al[cur]);
        const char* Rb = reinterpret_cast<const char*>(Brs[cur]);
        const char* Ib = reinterpret_cast<const char*>(Bis[cur]);
        #pragma unroll
        for (int ks = 0; ks < 2; ++ks) {
            bf16x8 af[4], brf[4], bif[4];
            #pragma unroll
            for (int mi = 0; mi < 4; ++mi) {
                const int ra = wr + mi * 16 + lrow;
                const uint32_t bo = (uint32_t)(ra * 128 + ks * 64 + lkb)
                                  ^ (uint32_t)((ra & 7) << 4);
                af[mi] = *reinterpret_cast<const bf16x8*>(Ab + bo);
            }
            #pragma unroll
            for (int ni = 0; ni < 4; ++ni) {
                const int rb = wc + ni * 16 + lrow;
                const uint32_t bo = (uint32_t)(rb * 128 + ks * 64 + lkb)
                                  ^ (uint32_t)((rb & 7) << 4);
                brf[ni] = *reinterpret_cast<const bf16x8*>(Rb + bo);
                bif[ni] = *reinterpret_cast<const bf16x8*>(Ib + bo);
            }
            #pragma unroll
            for (int mi = 0; mi < 4; ++mi) {
                #pragma unroll
                for (int ni = 0; ni < 4; ++ni) {
                    accr[mi][ni] = __builtin_amdgcn_mfma_f32_16x16x32_bf16(
                        af[mi], brf[ni], accr[mi][ni], 0, 0, 0);
                    acci[mi][ni] = __builtin_amdgcn_mfma_f32_16x16x32_bf16(
                        af[mi], bif[ni], acci[mi][ni], 0, 0, 0);
                }
            }
        }
        __builtin_amdgcn_s_barrier();
    }

    // ---- epilogue: C/D layout col = lane&15, row = (lane>>4)*4 + j ----
    const int rbase = m0 + wr + ((lane >> 4) << 2);
    const int cbase = n0 + wc + lrow;
    #pragma unroll
    for (int ni = 0; ni < 4; ++ni) {
        const int col = cbase + ni * 16;
        const float lam = LL[col];
        const float l2s = -log2f(1.0f + __expf(-lam));  // log2(sigmoid(lambda))
        const float bav = Ba[col];
        const float bxv = Bx[col];
        const int   kcx = col >> 6;
        const uint32_t colin = (uint32_t)((col & 63) << 1);
        const char* xbase = reinterpret_cast<const char*>(Xsw)
                          + (size_t)kcx * ((size_t)M_ * 128);
        #pragma unroll
        for (int mi = 0; mi < 4; ++mi) {
            #pragma unroll
            for (int j = 0; j < 4; ++j) {
                const int row = rbase + mi * 16 + j;
                const float zr = accr[mi][ni][j] + bav;
                const float zi = acci[mi][ni][j] + bxv;
                const float rv = 1.0f / (1.0f + __expf(-zr));
                const float iv = 1.0f / (1.0f + __expf(-zi));
                const float ee = 8.0f * rv * l2s;       // log2(a)
                const uint32_t inrow = ((uint32_t)(row * 128) + colin)
                                     ^ (uint32_t)((row & 7) << 4);
                const uint16_t xb = *reinterpret_cast<const uint16_t*>(xbase + inrow);
                const float xv  = bfbits2f((uint32_t)xb << 16);
                const float ixv = iv * xv;
                const uint16_t ebits  = __builtin_bit_cast(uint16_t, (__bf16)ee);
                const uint16_t ixbits = __builtin_bit_cast(uint16_t, (__bf16)ixv);
                EIX[(size_t)row * D_ + col] = (uint32_t)ebits | ((uint32_t)ixbits << 16);
            }
        }
    }
}

// ---------------------------------------------------------------------------
// K2: per-chunk summaries: P = prod a = 2^(sum e), hend = local scan from 0.
// ---------------------------------------------------------------------------
__global__ __launch_bounds__(256) void rg_scan_chunks(
    const uint32_t* __restrict__ EIX, float* __restrict__ P, float* __restrict__ HE)
{
    const int g = blockIdx.x * 256 + threadIdx.x;   // < B*NC*D = 262144
    const int d = g & (D_ - 1);
    const int c = (g >> 10) & (NC - 1);
    const int b = g >> 15;
    const size_t base = ((size_t)(b * T_ + c * CL)) * D_ + d;

    float h = 0.0f;
    float se = 0.0f;
    #pragma unroll 8
    for (int t = 0; t < CL; ++t) {
        const uint32_t u = EIX[base + (size_t)t * D_];
        const float e  = bfbits2f(u << 16);
        const float ix = bfbits2f(u & 0xffff0000u);
        const float a  = exp2f(e);
        const float gate = sqrtf(fmaxf((1.0f - a) * (1.0f + a), 1e-6f));
        h = fmaf(a, h, gate * ix);
        se += e;
    }
    const int sidx = (b * NC + c) * D_ + d;
    P[sidx]  = exp2f(se);
    HE[sidx] = h;
}

// ---------------------------------------------------------------------------
// K3: sequential combine over NC chunks per (b,d); seeds with h0.
// ---------------------------------------------------------------------------
__global__ __launch_bounds__(256) void rg_combine(
    const float* __restrict__ P, const float* __restrict__ HE,
    const float* __restrict__ H0, float* __restrict__ CI,
    float* __restrict__ HF)
{
    const int g = blockIdx.x * 256 + threadIdx.x;   // < B*D = 8192
    const int d = g & (D_ - 1);
    const int b = g >> 10;
    float carry = H0[g];
    #pragma unroll
    for (int c = 0; c < NC; ++c) {
        const int sidx = (b * NC + c) * D_ + d;
        CI[sidx] = carry;
        carry = fmaf(P[sidx], carry, HE[sidx]);
    }
    HF[g] = carry;
}

// ---------------------------------------------------------------------------
// K4: final intra-chunk scan with correct carry; writes h_t to OUT (write-only).
// ---------------------------------------------------------------------------
__global__ __launch_bounds__(256) void rg_scan_final(
    const uint32_t* __restrict__ EIX, const float* __restrict__ CI,
    float* __restrict__ OUT)
{
    const int g = blockIdx.x * 256 + threadIdx.x;   // < B*NC*D
    const int d = g & (D_ - 1);
    const int c = (g >> 10) & (NC - 1);
    const int b = g >> 15;
    const size_t base = ((size_t)(b * T_ + c * CL)) * D_ + d;

    float h = CI[(b * NC + c) * D_ + d];
    #pragma unroll 8
    for (int t = 0; t < CL; ++t) {
        const size_t idx = base + (size_t)t * D_;
        const uint32_t u = EIX[idx];
        const float e  = bfbits2f(u << 16);
        const float ix = bfbits2f(u & 0xffff0000u);
        const float a  = exp2f(e);
        const float gate = sqrtf(fmaxf((1.0f - a) * (1.0f + a), 1e-6f));
        h = fmaf(a, h, gate * ix);
        OUT[idx] = h;
    }
}

// ---------------------------------------------------------------------------
extern "C" void kernel_launch(void* const* d_in, const int* in_sizes, int n_in,
                              void* d_out, int out_size, void* d_ws, size_t ws_size,
                              hipStream_t stream)
{
    (void)in_sizes; (void)n_in; (void)out_size; (void)ws_size;
    const float* X  = (const float*)d_in[0];
    const float* H0 = (const float*)d_in[1];
    const float* Wa = (const float*)d_in[2];
    const float* Ba = (const float*)d_in[3];
    const float* Wx = (const float*)d_in[4];
    const float* Bx = (const float*)d_in[5];
    const float* LL = (const float*)d_in[6];

    // d_out doubles as scratch for the bf16-converted operands (dead before K4
    // rewrites every output element):
    //   [0,64MB)    Xsw   (bf16, swizzled k-chunked)
    //   [64,66MB)   Wasw  [66,68MB) Wxsw
    char* ob = (char*)d_out;
    __bf16* Xsw  = (__bf16*)ob;
    __bf16* Wasw = (__bf16*)(ob + ((size_t)M_ * K_ * 2));
    __bf16* Wxsw = (__bf16*)(ob + ((size_t)M_ * K_ * 2) + (size_t)K_ * D_ * 2);
    float*  OUT  = (float*)d_out;
    float*  HFINAL = OUT + (size_t)M_ * D_;    // h_final after outputs

    // ws: EIX (uint32, 128MB) | P | HE | CI (1MB each)  = 131 MB
    char* ws = (char*)d_ws;
    uint32_t* EIX = (uint32_t*)ws;
    float* P  = (float*)(ws + (size_t)M_ * D_ * 4);
    float* HE = P  + (size_t)B_ * NC * D_;
    float* CI = HE + (size_t)B_ * NC * D_;

    cvt_swz<<<dim3(M_ / 2), dim3(256), 0, stream>>>(X, Xsw, M_);
    cvt_swz<<<dim3(512), dim3(256), 0, stream>>>(Wa, Wasw, 1024);
    cvt_swz<<<dim3(512), dim3(256), 0, stream>>>(Wx, Wxsw, 1024);

    rg_gemm_gate<<<dim3((M_/BM) * (D_/BN)), dim3(512), 0, stream>>>(
        Xsw, Wasw, Wxsw, Ba, Bx, LL, EIX);

    rg_scan_chunks<<<dim3(B_ * NC * D_ / 256), dim3(256), 0, stream>>>(EIX, P, HE);
    rg_combine<<<dim3(B_ * D_ / 256), dim3(256), 0, stream>>>(P, HE, H0, CI, HFINAL);
    rg_scan_final<<<dim3(B_ * NC * D_ / 256), dim3(256), 0, stream>>>(EIX, CI, OUT);
}